// Round 7
// baseline (9605.376 us; speedup 1.0000x reference)
//
#include <hip/hip_runtime.h>

// Broadcast helper via v_readlane (uniform SGPR result) — pivot scalars only.
__device__ __forceinline__ int rdlane_i(int v, int l) {
    return __builtin_amdgcn_readlane(v, l);
}
__device__ __forceinline__ float rdlane_f(float v, int l) {
    return __int_as_float(__builtin_amdgcn_readlane(__float_as_int(v), l));
}

// One butterfly step of a 64-lane INTEGER max (order-equivalent to float
// max for our keys: alive keys are non-negative floats, dead keys are
// -inf-packed => hugely negative ints; bound_ctrl injects 0 which never
// beats a real alive key).
template <int CTRL>
__device__ __forceinline__ int dpp_imax_step(int x) {
    int t = __builtin_amdgcn_update_dpp(0, x, CTRL, 0xF, 0xF, true);
    return (t > x) ? t : x;
}

// Full 64-lane int max; result valid in lane 63.
__device__ __forceinline__ int wave_imax_to_lane63(int x) {
    x = dpp_imax_step<0xB1>(x);   // xor 1
    x = dpp_imax_step<0x4E>(x);   // xor 2
    x = dpp_imax_step<0x141>(x);  // row_half_mirror (xor within 8)
    x = dpp_imax_step<0x140>(x);  // row_mirror      (xor within 16)
    x = dpp_imax_step<0x142>(x);  // row_bcast15     (16 -> 32)
    x = dpp_imax_step<0x143>(x);  // row_bcast31     (32 -> 64)
    return x;
}

// One wave = one 64x64 matrix, lane i owns ROW i in registers A[0..63].
// Block = 128 threads: wave 0 -> spin-up matrix, wave 1 -> spin-dn matrix.
//
// EVIDENCE TRAIL (R0-R6):
//   - VALU cycles/wave ~33K in R0-R5, invariant under occupancy (22-83%)
//     and register homing (AGPR/arch/asm-pinned). Stream floor is ~11K.
//   - R6 (ds_bpermute broadcast): 410us, VALUBusy 28% -> LGKM-serialized.
//     The broadcast op is the bottleneck either way.
//   - Remaining explanation for the 3x: VALU->SGPR-write (v_readlane)
//     followed immediately by a VALU read of that SGPR stalls ~13 cy
//     (hw-interlocked wait states). Every prior version had the
//     readlane->fmac pair back-to-back on ONE SGPR.
// FIX: batch 8 readlanes into 8 DIFFERENT SGPRs, then 8 fmacs — every
// SGPR write gets >=7 intervening VALU ops before its consumer. Separate
// asm statements (not glued) so the scheduler can interleave further.
//
// waves_per_eu(2,2): only config measured to home A[64] architecturally
// (R5: VGPR_Count=88 >= array size; all others spilled A[] to AGPR and
// paid v_accvgpr_read/write per touch). Kept.
__global__ __launch_bounds__(128)
__attribute__((amdgpu_waves_per_eu(2, 2)))
void slater_logdet_kernel(
        const float* __restrict__ rs, const float* __restrict__ log_alpha_p,
        float* __restrict__ out) {
    const int b    = blockIdx.x;
    const int tid  = threadIdx.x;
    const int wave = tid >> 6;   // 0 = up, 1 = dn
    const int lane = tid & 63;

    const float Lbox = 10.0f;
    const float PI_F = 3.14159265358979323846f;

    float alpha = __expf(log_alpha_p[0]);
    alpha = fminf(fmaxf(alpha, 0.5f / (Lbox * Lbox)), 200.0f / (Lbox * Lbox));

    // Electron position for this lane (row index = electron index).
    const float* rp = rs + (size_t)b * 384 + (size_t)(wave * 64 + lane) * 3;
    float x = rp[0], y = rp[1], z = rp[2];

    float sx, cx, sy, cy, sz, cz;
    __sincosf(x * (PI_F / Lbox), &sx, &cx);
    __sincosf(y * (PI_F / Lbox), &sy, &cy);
    __sincosf(z * (PI_F / Lbox), &sz, &cz);

    // Separable build: Phi[i][j] = ex[mx]*ey[my]*ez[mz], j = mx*16+my*4+mz.
    // Only 12 exps + ~80 muls per lane (vs 64 exps in the column layout).
    const float off = wave ? 0.5f : 0.0f;
    const float LPI = Lbox / PI_F;
    float ex[4], ey[4], ez[4];
#pragma unroll
    for (int m = 0; m < 4; ++m) {
        float sp, cp;
        __sincosf((PI_F * 0.25f) * ((float)m + off), &sp, &cp);
        float dx = LPI * (sx * cp - cx * sp);
        float dy = LPI * (sy * cp - cy * sp);
        float dz = LPI * (sz * cp - cz * sp);
        ex[m] = __expf(-alpha * dx * dx);
        ey[m] = __expf(-alpha * dy * dy);
        ez[m] = __expf(-alpha * dz * dz);
    }
    float exy[16];
#pragma unroll
    for (int q = 0; q < 16; ++q) exy[q] = ex[q >> 2] * ey[q & 3];
    float A[64];
#pragma unroll
    for (int j = 0; j < 64; ++j) A[j] = exy[j >> 2] * ez[j & 3];

    // LU with partial pivoting, row-owner layout, NO physical row swap:
    // pivot rows stay in their lane; flag = -inf marks them dead so the
    // argmax never selects them again. det sign is irrelevant (log|det|).
    //
    // Pivot search: pack the lane index into the low 6 bits of the key's
    // mantissa and take an integer max — the winning lane index falls out
    // of the max result itself (no ballot/ffs).
    float flag   = 0.0f;   // 0 while alive, -inf once used as pivot row
    float logdet = 0.0f;
#pragma unroll
    for (int k = 0; k < 64; ++k) {
        // key = |A[k]| for alive rows, -inf for dead rows (one v_add w/ |mod|)
        float key = fabsf(A[k]) + flag;
        int   ki  = (__float_as_int(key) & ~63) | lane;  // keep sign bit!
        int   g   = rdlane_i(wave_imax_to_lane63(ki), 63);
        int   p   = g & 63;                        // pivot row's physical lane

        float pv  = rdlane_f(A[k], p);
        float inv = __builtin_amdgcn_rcpf(pv);
        inv = inv * (2.0f - pv * inv);             // 1 Newton step (~0.5 ulp)
        logdet += __logf(fabsf(pv));

        // Mark pivot row dead for future argmaxes.
        flag = (lane == p) ? -__builtin_huge_valf() : flag;

        // One multiplier per lane; lane p gets m~=1 and self-annihilates
        // (its row is never read again), dead lanes have A[k]=~0.
        float m  = A[k] * inv;
        float nm = -m;

        // Rank-1 update, 8-way batched to hide the readlane->SGPR->VALU
        // RAW hazard: 8 v_readlane into 8 DISTINCT SGPRs, then 8 v_fmac.
        // Separate (non-glued) asm statements let the scheduler interleave
        // across batches too. All loop bounds constant after unroll.
#pragma unroll
        for (int j = k + 1; j < 64; j += 8) {
            float sv[8];
#pragma unroll
            for (int t = 0; t < 8; ++t) {
                if (j + t < 64) {
                    asm("v_readlane_b32 %0, %1, %2"
                        : "=s"(sv[t]) : "v"(A[j + t]), "s"(p));
                }
            }
#pragma unroll
            for (int t = 0; t < 8; ++t) {
                if (j + t < 64) {
                    asm("v_fmac_f32 %0, %1, %2"
                        : "+v"(A[j + t]) : "s"(sv[t]), "v"(nm));
                }
            }
        }
    }

    // logdet is lane-uniform. Combine the two spins.
    __shared__ float partial[2];
    if (lane == 0) partial[wave] = logdet;
    __syncthreads();
    if (tid == 0) out[b] = partial[0] + partial[1];
}

extern "C" void kernel_launch(void* const* d_in, const int* in_sizes, int n_in,
                              void* d_out, int out_size, void* d_ws, size_t ws_size,
                              hipStream_t stream) {
    const float* rs = (const float*)d_in[0];
    const float* la = (const float*)d_in[1];
    float* out      = (float*)d_out;
    slater_logdet_kernel<<<out_size, 128, 0, stream>>>(rs, la, out);
}

// Round 8
// 2231.504 us; speedup vs baseline: 4.3044x; 4.3044x over previous
//
#include <hip/hip_runtime.h>

// Broadcast helper via v_readlane (uniform SGPR result) — pivot scalars only.
__device__ __forceinline__ int rdlane_i(int v, int l) {
    return __builtin_amdgcn_readlane(v, l);
}
__device__ __forceinline__ float rdlane_f(float v, int l) {
    return __int_as_float(__builtin_amdgcn_readlane(__float_as_int(v), l));
}

// One butterfly step of a 64-lane INTEGER max (order-equivalent to float
// max for our keys: alive keys are non-negative floats, dead keys are
// -inf-packed => hugely negative ints; bound_ctrl injects 0 which never
// beats a real alive key).
template <int CTRL>
__device__ __forceinline__ int dpp_imax_step(int x) {
    int t = __builtin_amdgcn_update_dpp(0, x, CTRL, 0xF, 0xF, true);
    return (t > x) ? t : x;
}

// Full 64-lane int max; result valid in lane 63.
__device__ __forceinline__ int wave_imax_to_lane63(int x) {
    x = dpp_imax_step<0xB1>(x);   // xor 1
    x = dpp_imax_step<0x4E>(x);   // xor 2
    x = dpp_imax_step<0x141>(x);  // row_half_mirror (xor within 8)
    x = dpp_imax_step<0x140>(x);  // row_mirror      (xor within 16)
    x = dpp_imax_step<0x142>(x);  // row_bcast15     (16 -> 32)
    x = dpp_imax_step<0x143>(x);  // row_bcast31     (32 -> 64)
    return x;
}

// 8-column rank-1 update block: 8 v_readlane into 8 DISTINCT named SGPRs,
// then 8 v_fmac. Every SGPR write has 7 intervening instructions (>=14 cy)
// before its VALU consumer -> the VALU->SGPR->VALU wait-state is hidden.
// NAMED scalars, never an array (R7: an sv[8] array + "=s" constraints went
// to scratch: LDS 33KB, 5.5e9 bank conflicts, 9.6ms). One asm block fixes
// the internal order by construction.
#define UPD8(J)                                                              \
    do {                                                                     \
        float t0, t1, t2, t3, t4, t5, t6, t7;                                \
        asm("v_readlane_b32 %8, %0, %17\n\t"                                 \
            "v_readlane_b32 %9, %1, %17\n\t"                                 \
            "v_readlane_b32 %10, %2, %17\n\t"                                \
            "v_readlane_b32 %11, %3, %17\n\t"                                \
            "v_readlane_b32 %12, %4, %17\n\t"                                \
            "v_readlane_b32 %13, %5, %17\n\t"                                \
            "v_readlane_b32 %14, %6, %17\n\t"                                \
            "v_readlane_b32 %15, %7, %17\n\t"                                \
            "v_fmac_f32 %0, %8, %16\n\t"                                     \
            "v_fmac_f32 %1, %9, %16\n\t"                                     \
            "v_fmac_f32 %2, %10, %16\n\t"                                    \
            "v_fmac_f32 %3, %11, %16\n\t"                                    \
            "v_fmac_f32 %4, %12, %16\n\t"                                    \
            "v_fmac_f32 %5, %13, %16\n\t"                                    \
            "v_fmac_f32 %6, %14, %16\n\t"                                    \
            "v_fmac_f32 %7, %15, %16"                                        \
            : "+v"(A[(J) + 0]), "+v"(A[(J) + 1]), "+v"(A[(J) + 2]),          \
              "+v"(A[(J) + 3]), "+v"(A[(J) + 4]), "+v"(A[(J) + 5]),          \
              "+v"(A[(J) + 6]), "+v"(A[(J) + 7]),                            \
              "=&s"(t0), "=&s"(t1), "=&s"(t2), "=&s"(t3),                    \
              "=&s"(t4), "=&s"(t5), "=&s"(t6), "=&s"(t7)                     \
            : "v"(nm), "s"(p));                                              \
    } while (0)

// One wave = one 64x64 matrix, lane i owns ROW i in registers A[0..63].
// Block = 128 threads: wave 0 -> spin-up matrix, wave 1 -> spin-dn matrix.
//
// EVIDENCE TRAIL (R0-R7):
//   - VALU cycles/wave ~33K in R0-R5, invariant under occupancy (22-83%)
//     and register homing (AGPR / arch / asm-pinned); stream floor ~12K.
//   - R6 ds_bpermute broadcast: 410us, VALUBusy 28% — LGKM-serialized.
//   - Working theory: each back-to-back v_readlane(SGPR write)->v_fmac
//     (SGPR read) pair pays ~10 hw wait-state cycles; R5 additionally
//     WAW-serialized on a single reused s_tmp. 2016 pairs ~= the 21K gap.
//   - R7 disproved nothing (temp ARRAY went to scratch; experiment void).
// This round: 8-wide batiched blocks with named SGPR temps (see UPD8).
// Update range rounded DOWN to a multiple of 8: re-updating dead columns
// is harmless (never read again; |m|<=1 keeps growth << fp32 range) and
// keeps every block exactly 8 wide.
//
// waves_per_eu(2,2): only config measured to home A[64] architecturally
// (R5: VGPR_Count=88). Kept.
__global__ __launch_bounds__(128)
__attribute__((amdgpu_waves_per_eu(2, 2)))
void slater_logdet_kernel(
        const float* __restrict__ rs, const float* __restrict__ log_alpha_p,
        float* __restrict__ out) {
    const int b    = blockIdx.x;
    const int tid  = threadIdx.x;
    const int wave = tid >> 6;   // 0 = up, 1 = dn
    const int lane = tid & 63;

    const float Lbox = 10.0f;
    const float PI_F = 3.14159265358979323846f;

    float alpha = __expf(log_alpha_p[0]);
    alpha = fminf(fmaxf(alpha, 0.5f / (Lbox * Lbox)), 200.0f / (Lbox * Lbox));

    // Electron position for this lane (row index = electron index).
    const float* rp = rs + (size_t)b * 384 + (size_t)(wave * 64 + lane) * 3;
    float x = rp[0], y = rp[1], z = rp[2];

    float sx, cx, sy, cy, sz, cz;
    __sincosf(x * (PI_F / Lbox), &sx, &cx);
    __sincosf(y * (PI_F / Lbox), &sy, &cy);
    __sincosf(z * (PI_F / Lbox), &sz, &cz);

    // Separable build: Phi[i][j] = ex[mx]*ey[my]*ez[mz], j = mx*16+my*4+mz.
    const float off = wave ? 0.5f : 0.0f;
    const float LPI = Lbox / PI_F;
    float ex[4], ey[4], ez[4];
#pragma unroll
    for (int m = 0; m < 4; ++m) {
        float sp, cp;
        __sincosf((PI_F * 0.25f) * ((float)m + off), &sp, &cp);
        float dx = LPI * (sx * cp - cx * sp);
        float dy = LPI * (sy * cp - cy * sp);
        float dz = LPI * (sz * cp - cz * sp);
        ex[m] = __expf(-alpha * dx * dx);
        ey[m] = __expf(-alpha * dy * dy);
        ez[m] = __expf(-alpha * dz * dz);
    }
    float exy[16];
#pragma unroll
    for (int q = 0; q < 16; ++q) exy[q] = ex[q >> 2] * ey[q & 3];
    float A[64];
#pragma unroll
    for (int j = 0; j < 64; ++j) A[j] = exy[j >> 2] * ez[j & 3];

    // LU with partial pivoting, row-owner layout, NO physical row swap:
    // pivot rows stay in their lane; flag = -inf marks them dead so the
    // argmax never selects them again. det sign is irrelevant (log|det|).
    //
    // Pivot search: pack the lane index into the low 6 bits of the key's
    // mantissa and take an integer max — the winning lane index falls out
    // of the max result itself (no ballot/ffs).
    float flag   = 0.0f;   // 0 while alive, -inf once used as pivot row
    float logdet = 0.0f;
#pragma unroll
    for (int k = 0; k < 64; ++k) {
        // key = |A[k]| for alive rows, -inf for dead rows
        float key = fabsf(A[k]) + flag;
        int   ki  = (__float_as_int(key) & ~63) | lane;  // keep sign bit!
        int   g   = rdlane_i(wave_imax_to_lane63(ki), 63);
        int   p   = g & 63;                        // pivot row's physical lane

        float pv  = rdlane_f(A[k], p);
        float inv = __builtin_amdgcn_rcpf(pv);
        inv = inv * (2.0f - pv * inv);             // 1 Newton step (~0.5 ulp)
        logdet += __logf(fabsf(pv));

        // Mark pivot row dead for future argmaxes.
        flag = (lane == p) ? -__builtin_huge_valf() : flag;

        // One multiplier per lane; lane p gets m~=1 and self-annihilates,
        // dead lanes have A[k]~=0. nm computed from A[k] BEFORE the blocks
        // below overwrite it (SSA dependence enforces the order).
        float nm = A[k] * (-inv);

        // 8-wide blocks from the aligned start; includes <=7 dead columns
        // (harmless, see header) and column k itself (becomes ~0, standard
        // elimination; never read again).
        const int j0 = (k + 1) & ~7;
#pragma unroll
        for (int j = j0; j < 64; j += 8) {
            UPD8(j);
        }
    }

    // logdet is lane-uniform. Combine the two spins.
    __shared__ float partial[2];
    if (lane == 0) partial[wave] = logdet;
    __syncthreads();
    if (tid == 0) out[b] = partial[0] + partial[1];
}

extern "C" void kernel_launch(void* const* d_in, const int* in_sizes, int n_in,
                              void* d_out, int out_size, void* d_ws, size_t ws_size,
                              hipStream_t stream) {
    const float* rs = (const float*)d_in[0];
    const float* la = (const float*)d_in[1];
    float* out      = (float*)d_out;
    slater_logdet_kernel<<<out_size, 128, 0, stream>>>(rs, la, out);
}

// Round 9
// 307.575 us; speedup vs baseline: 31.2294x; 7.2552x over previous
//
#include <hip/hip_runtime.h>

// Broadcast helper via v_readlane (uniform SGPR result) — pivot scalars only.
__device__ __forceinline__ int rdlane_i(int v, int l) {
    return __builtin_amdgcn_readlane(v, l);
}
__device__ __forceinline__ float rdlane_f(float v, int l) {
    return __int_as_float(__builtin_amdgcn_readlane(__float_as_int(v), l));
}

// One butterfly step of a 64-lane INTEGER max (order-equivalent to float
// max for our keys: alive keys are non-negative floats, dead keys are
// -inf-packed => hugely negative ints; bound_ctrl injects 0 which never
// beats a real alive key).
template <int CTRL>
__device__ __forceinline__ int dpp_imax_step(int x) {
    int t = __builtin_amdgcn_update_dpp(0, x, CTRL, 0xF, 0xF, true);
    return (t > x) ? t : x;
}

// Full 64-lane int max; result valid in lane 63.
__device__ __forceinline__ int wave_imax_to_lane63(int x) {
    x = dpp_imax_step<0xB1>(x);   // xor 1
    x = dpp_imax_step<0x4E>(x);   // xor 2
    x = dpp_imax_step<0x141>(x);  // row_half_mirror (xor within 8)
    x = dpp_imax_step<0x140>(x);  // row_mirror      (xor within 16)
    x = dpp_imax_step<0x142>(x);  // row_bcast15     (16 -> 32)
    x = dpp_imax_step<0x143>(x);  // row_bcast31     (32 -> 64)
    return x;
}

// 8-column rank-1 update block: 8 v_readlane into 8 DISTINCT named SGPRs,
// then 8 v_fmac. Every SGPR write gets 7 intervening instructions (>=14cy)
// before its VALU consumer -> the VALU->SGPR-write->VALU-read wait-state
// (~9cy when back-to-back; R5's 18K-cycle gap) is fully hidden.
// Named scalars only — R7's sv[8] array went to scratch.
#define UPD8(J)                                                              \
    do {                                                                     \
        float t0, t1, t2, t3, t4, t5, t6, t7;                                \
        asm("v_readlane_b32 %8, %0, %17\n\t"                                 \
            "v_readlane_b32 %9, %1, %17\n\t"                                 \
            "v_readlane_b32 %10, %2, %17\n\t"                                \
            "v_readlane_b32 %11, %3, %17\n\t"                                \
            "v_readlane_b32 %12, %4, %17\n\t"                                \
            "v_readlane_b32 %13, %5, %17\n\t"                                \
            "v_readlane_b32 %14, %6, %17\n\t"                                \
            "v_readlane_b32 %15, %7, %17\n\t"                                \
            "v_fmac_f32 %0, %8, %16\n\t"                                     \
            "v_fmac_f32 %1, %9, %16\n\t"                                     \
            "v_fmac_f32 %2, %10, %16\n\t"                                    \
            "v_fmac_f32 %3, %11, %16\n\t"                                    \
            "v_fmac_f32 %4, %12, %16\n\t"                                    \
            "v_fmac_f32 %5, %13, %16\n\t"                                    \
            "v_fmac_f32 %6, %14, %16\n\t"                                    \
            "v_fmac_f32 %7, %15, %16"                                        \
            : "+v"(A[(J) + 0]), "+v"(A[(J) + 1]), "+v"(A[(J) + 2]),          \
              "+v"(A[(J) + 3]), "+v"(A[(J) + 4]), "+v"(A[(J) + 5]),          \
              "+v"(A[(J) + 6]), "+v"(A[(J) + 7]),                            \
              "=&s"(t0), "=&s"(t1), "=&s"(t2), "=&s"(t3),                    \
              "=&s"(t4), "=&s"(t5), "=&s"(t6), "=&s"(t7)                     \
            : "v"(nm), "s"(p));                                              \
    } while (0)

// One pivot step, K a TEMPLATE parameter: every A[] index in this function
// is a compile-time constant by construction. R8's runtime-trip-count
// inner loop (j0 = (k+1)&~7 with loop-variable k) defeated unrolling ->
// dynamic A[j] indexing -> the whole array demoted to scratch
// (LDS_Block_Size 33280, 1.16e9 bank conflicts, 2.2ms). Template
// recursion makes that impossible.
template <int K>
__device__ __forceinline__ void lu_step(float (&A)[64], float& flag,
                                        float& logdet, const int lane) {
    // key = |A[K]| for alive rows, -inf for dead rows; lane index packed
    // into the low 6 mantissa bits so the argmax returns its own winner.
    float key = fabsf(A[K]) + flag;
    int   ki  = (__float_as_int(key) & ~63) | lane;
    int   g   = rdlane_i(wave_imax_to_lane63(ki), 63);
    int   p   = g & 63;                        // pivot row's physical lane

    float pv  = rdlane_f(A[K], p);
    float inv = __builtin_amdgcn_rcpf(pv);
    inv = inv * (2.0f - pv * inv);             // 1 Newton step (~0.5 ulp)
    logdet += __logf(fabsf(pv));

    // Mark pivot row dead for future argmaxes.
    flag = (lane == p) ? -__builtin_huge_valf() : flag;

    // One multiplier per lane; lane p gets m~=1 and self-annihilates,
    // dead lanes have A[K]~=0. nm is read before the blocks overwrite A[K].
    float nm = A[K] * (-inv);

    // 8-wide blocks from the aligned start: constexpr trip count -> full
    // unroll guaranteed. Includes <=7 already-eliminated columns; harmless
    // (never read again: argmax masks dead ROWS via flag, and columns < K
    // are never revisited; |nm|<=1 keeps growth linear, far from overflow).
    constexpr int J0 = (K + 1) & ~7;
#pragma unroll
    for (int j = J0; j < 64; j += 8) {
        UPD8(j);
    }
}

template <int K>
__device__ __forceinline__ void lu_run(float (&A)[64], float& flag,
                                       float& logdet, const int lane) {
    lu_step<K>(A, flag, logdet, lane);
    if constexpr (K + 1 < 64) lu_run<K + 1>(A, flag, logdet, lane);
}

// One wave = one 64x64 matrix, lane i owns ROW i in registers A[0..63].
// Block = 128 threads: wave 0 -> spin-up matrix, wave 1 -> spin-dn matrix.
//
// EVIDENCE TRAIL (R0-R8):
//   - R0-R5: ~33K VALU-busy cycles/wave, invariant under occupancy
//     (22-83%) and register homing. R5 (arch-homed, VGPR=88, glued
//     readlane->fmac asm) stream is ~5.9K instr = ~11.8K issue cycles;
//     the ~18K-cycle gap == 2016 pairs x ~9cy RAW wait-state
//     (VALU SGPR-write -> VALU SGPR-read). VALUBusy counts wait-states.
//   - R6 (ds_bpermute): 410us, LGKM-serialized. Broadcast must stay VALU.
//   - R7/R8: batching attempts void — temps/array hit scratch (rule:
//     any runtime-indexed array -> scratch). Fixed via templates above.
// waves_per_eu(2,2): only config measured to home A[64] architecturally
// (R5/R8: VGPR_Count=88). Kept.
__global__ __launch_bounds__(128)
__attribute__((amdgpu_waves_per_eu(2, 2)))
void slater_logdet_kernel(
        const float* __restrict__ rs, const float* __restrict__ log_alpha_p,
        float* __restrict__ out) {
    const int b    = blockIdx.x;
    const int tid  = threadIdx.x;
    const int wave = tid >> 6;   // 0 = up, 1 = dn
    const int lane = tid & 63;

    const float Lbox = 10.0f;
    const float PI_F = 3.14159265358979323846f;

    float alpha = __expf(log_alpha_p[0]);
    alpha = fminf(fmaxf(alpha, 0.5f / (Lbox * Lbox)), 200.0f / (Lbox * Lbox));

    // Electron position for this lane (row index = electron index).
    const float* rp = rs + (size_t)b * 384 + (size_t)(wave * 64 + lane) * 3;
    float x = rp[0], y = rp[1], z = rp[2];

    float sx, cx, sy, cy, sz, cz;
    __sincosf(x * (PI_F / Lbox), &sx, &cx);
    __sincosf(y * (PI_F / Lbox), &sy, &cy);
    __sincosf(z * (PI_F / Lbox), &sz, &cz);

    // Separable build: Phi[i][j] = ex[mx]*ey[my]*ez[mz], j = mx*16+my*4+mz.
    const float off = wave ? 0.5f : 0.0f;
    const float LPI = Lbox / PI_F;
    float ex[4], ey[4], ez[4];
#pragma unroll
    for (int m = 0; m < 4; ++m) {
        float sp, cp;
        __sincosf((PI_F * 0.25f) * ((float)m + off), &sp, &cp);
        float dx = LPI * (sx * cp - cx * sp);
        float dy = LPI * (sy * cp - cy * sp);
        float dz = LPI * (sz * cp - cz * sp);
        ex[m] = __expf(-alpha * dx * dx);
        ey[m] = __expf(-alpha * dy * dy);
        ez[m] = __expf(-alpha * dz * dz);
    }
    float exy[16];
#pragma unroll
    for (int q = 0; q < 16; ++q) exy[q] = ex[q >> 2] * ey[q & 3];
    float A[64];
#pragma unroll
    for (int j = 0; j < 64; ++j) A[j] = exy[j >> 2] * ez[j & 3];

    // LU with partial pivoting, row-owner layout, NO physical row swap.
    float flag   = 0.0f;   // 0 while alive, -inf once used as pivot row
    float logdet = 0.0f;
    lu_run<0>(A, flag, logdet, lane);

    // logdet is lane-uniform. Combine the two spins.
    __shared__ float partial[2];
    if (lane == 0) partial[wave] = logdet;
    __syncthreads();
    if (tid == 0) out[b] = partial[0] + partial[1];
}

extern "C" void kernel_launch(void* const* d_in, const int* in_sizes, int n_in,
                              void* d_out, int out_size, void* d_ws, size_t ws_size,
                              hipStream_t stream) {
    const float* rs = (const float*)d_in[0];
    const float* la = (const float*)d_in[1];
    float* out      = (float*)d_out;
    slater_logdet_kernel<<<out_size, 128, 0, stream>>>(rs, la, out);
}